// Round 6
// baseline (338.081 us; speedup 1.0000x reference)
//
#include <hip/hip_runtime.h>
#include <stdint.h>

// B=16, S=2048, D=128 attention, per-query scale folded into Q (with log2e),
// online softmax in exp2 domain, exact JAX partitionable-threefry dropout
// (key 42, p=0.1), @V.
// Round 6: split-K flash — 512-thread blocks (4 q-groups x 2 key-phases)
// -> 4 waves/SIMD; f16 single-product QK^T; f16 P/V; end-of-loop (m,l,O)
// merge of the two key-phase waves through LDS.

#define B_ 16
#define S_ 2048
#define D_ 128
#define TQ 64     // q rows per block (4 groups x 16)
#define TK 64     // keys staged per iteration (each wave consumes 32)
#define KSTR 136  // f16 stride for K rows (128+8)
#define VSTR 72   // f16 stride for V^T rows (64+8)
#define PSTR 40   // f16 stride for per-wave P rows (32+8)

typedef float f32x4 __attribute__((ext_vector_type(4)));
typedef _Float16 f16x8 __attribute__((ext_vector_type(8)));
typedef _Float16 f16x2 __attribute__((ext_vector_type(2)));

// DPP row_ror reductions over the 16 lanes of a row group.
#define DPP_ROR(x, ctrl) \
  __int_as_float(__builtin_amdgcn_update_dpp(0, __float_as_int(x), (ctrl), 0xf, 0xf, true))
__device__ __forceinline__ float row16_max(float x) {
  x = fmaxf(x, DPP_ROR(x, 0x128));
  x = fmaxf(x, DPP_ROR(x, 0x124));
  x = fmaxf(x, DPP_ROR(x, 0x122));
  x = fmaxf(x, DPP_ROR(x, 0x121));
  return x;
}
__device__ __forceinline__ float row16_sum(float x) {
  x += DPP_ROR(x, 0x128);
  x += DPP_ROR(x, 0x124);
  x += DPP_ROR(x, 0x122);
  x += DPP_ROR(x, 0x121);
  return x;
}

// threefry2x32, 20 rounds, key = (0, 42)  [jax.random.key(42)]
__device__ __forceinline__ uint2 threefry2x32_0_42(uint32_t x0, uint32_t x1) {
  const uint32_t k0 = 0u, k1 = 42u;
  const uint32_t k2 = 0x1BD11BDAu ^ k0 ^ k1;
  x0 += k0; x1 += k1;
#define TFR(r) { x0 += x1; x1 = __builtin_rotateleft32(x1, r); x1 ^= x0; }
  TFR(13) TFR(15) TFR(26) TFR(6)
  x0 += k1; x1 += k2 + 1u;
  TFR(17) TFR(29) TFR(16) TFR(24)
  x0 += k2; x1 += k0 + 2u;
  TFR(13) TFR(15) TFR(26) TFR(6)
  x0 += k0; x1 += k1 + 3u;
  TFR(17) TFR(29) TFR(16) TFR(24)
  x0 += k1; x1 += k2 + 4u;
  TFR(13) TFR(15) TFR(26) TFR(6)
  x0 += k2; x1 += k0 + 5u;
#undef TFR
  return make_uint2(x0, x1);
}

// HW-verified (round 2): partitionable path, counter (0, j), xor-fold.
__device__ __forceinline__ uint32_t jax_bits(uint32_t j) {
  const uint2 tf = threefry2x32_0_42(0u, j);
  return tf.x ^ tf.y;
}

__global__ __launch_bounds__(512, 4)
void attn_mfma_kernel(const float* __restrict__ Q, const float* __restrict__ K,
                      const float* __restrict__ V, const float* __restrict__ ISF,
                      const float* __restrict__ DP, float* __restrict__ OUT) {
  __shared__ __align__(16) char smem[46080];
  _Float16* const sK  = (_Float16*)smem;               // 64x136 f16 = 17408 B
  _Float16* const sVT = (_Float16*)(smem + 17408);     // 128x72 f16 = 18432 B
  _Float16* const sP  = (_Float16*)(smem + 35840);     // 8 x 16x40 f16 = 10240 B
  // end-of-loop merge scratch (overlays sK/sVT after final barrier):
  float* const sO1 = (float*)smem;                     // 4 x 16x128 f32 = 32768 B
  float* const sM1 = (float*)(smem + 32768);           // 64 f32
  float* const sL1 = (float*)(smem + 33024);           // 64 f32

  const int t    = threadIdx.x;
  const int lane = t & 63;
  const int l15  = lane & 15;
  const int quad = lane >> 4;
  const int w    = t >> 6;
  const int qg   = w & 3;        // q-group (16 rows)
  const int kph  = w >> 2;       // key phase: 0 = keys [0,32), 1 = [32,64) of tile
  const int b    = blockIdx.y;
  const int qw   = blockIdx.x * TQ + qg * 16;

  const float kp = 1.0f - DP[0];
  const uint32_t TH9 = (__float_as_uint(1.0f + kp) & 0x7FFFFFu) << 9;

  float m_[4], l_[4];
  uint32_t jq[4];
  #pragma unroll
  for (int r = 0; r < 4; ++r) {
    m_[r] = -INFINITY;
    l_[r] = 0.0f;
    jq[r] = ((uint32_t)b << 22) + (uint32_t)(qw + quad * 4 + r) * (uint32_t)S_;
  }

  // ---- Q fragments, f16, per-query 1/isf and log2(e) folded in ----
  f16x8 qf[4];
  {
    const float qs = 1.4426950408889634f / ISF[b * S_ + qw + l15];
    const float* qp = Q + ((size_t)(b * S_ + qw + l15)) * D_;
    #pragma unroll
    for (int c = 0; c < 4; ++c) {
      const float4 a = *(const float4*)(qp + c * 32 + quad * 8);
      const float4 d2 = *(const float4*)(qp + c * 32 + quad * 8 + 4);
      const float xs[8] = {a.x, a.y, a.z, a.w, d2.x, d2.y, d2.z, d2.w};
      f16x8 h;
      #pragma unroll
      for (int j = 0; j < 8; ++j) h[j] = (_Float16)(xs[j] * qs);
      qf[c] = h;
    }
  }

  f32x4 accO[8];
  #pragma unroll
  for (int i = 0; i < 8; ++i) accO[i] = (f32x4){0.f, 0.f, 0.f, 0.f};

  _Float16* const pwv = &sP[w * 16 * PSTR];

  // staging decomposition (512 threads)
  const int krow = t >> 3, kcol = (t & 7) * 16;        // K: 64 rows x 128
  const int vp = t & 31, dseg = (t >> 5) * 8;          // V: 32 key-pairs x 8 d

  for (int kt = 0; kt < S_ / TK; ++kt) {
    __syncthreads();   // A: all waves done reading previous tile

    // ---- stage K tile -> f16 LDS ----
    {
      const float* gk = K + ((size_t)(b * S_ + kt * TK + krow)) * D_ + kcol;
      float kf[16];
      #pragma unroll
      for (int i = 0; i < 4; ++i) *(float4*)&kf[i * 4] = *(const float4*)(gk + i * 4);
      #pragma unroll
      for (int g = 0; g < 2; ++g) {
        f16x8 h;
        #pragma unroll
        for (int j = 0; j < 8; ++j) h[j] = (_Float16)kf[g * 8 + j];
        *(f16x8*)&sK[krow * KSTR + kcol + g * 8] = h;
      }
    }
    // ---- stage V transposed -> f16 LDS (packed key-pair b32 writes) ----
    {
      const float* gv = V + ((size_t)(b * S_ + kt * TK + 2 * vp)) * D_ + dseg;
      float v0[8], v1[8];
      #pragma unroll
      for (int i = 0; i < 2; ++i) {
        *(float4*)&v0[i * 4] = *(const float4*)(gv + i * 4);
        *(float4*)&v1[i * 4] = *(const float4*)(gv + D_ + i * 4);
      }
      #pragma unroll
      for (int d = 0; d < 8; ++d) {
        f16x2 h = {(_Float16)v0[d], (_Float16)v1[d]};
        *(f16x2*)&sVT[(dseg + d) * VSTR + 2 * vp] = h;
      }
    }
    __syncthreads();   // B: tile visible

    // ---- QK^T: 16 q-rows x 32 keys (this wave's phase), f16 single ----
    f32x4 s[2];
    #pragma unroll
    for (int n = 0; n < 2; ++n) {
      f32x4 acc = (f32x4){0.f, 0.f, 0.f, 0.f};
      #pragma unroll
      for (int c = 0; c < 4; ++c) {
        const f16x8 bh = *(const f16x8*)&sK[(kph * 32 + n * 16 + l15) * KSTR + c * 32 + quad * 8];
        acc = __builtin_amdgcn_mfma_f32_16x16x32_f16(qf[c], bh, acc, 0, 0, 0);
      }
      s[n] = acc;
    }

    // ---- online softmax (exp2 domain) over this wave's 32 keys ----
    float mx[4];
    #pragma unroll
    for (int r = 0; r < 4; ++r) mx[r] = row16_max(fmaxf(s[0][r], s[1][r]));
    int changed = 0;
    #pragma unroll
    for (int r = 0; r < 4; ++r) changed |= (mx[r] > m_[r]);
    if (__ballot(changed) != 0ull) {
      #pragma unroll
      for (int r = 0; r < 4; ++r) {
        const float mnew = fmaxf(m_[r], mx[r]);
        const float alpha = __builtin_amdgcn_exp2f(m_[r] - mnew);  // exp2(-inf)=0
        m_[r] = mnew;
        l_[r] *= alpha;
        #pragma unroll
        for (int i = 0; i < 8; ++i) accO[i][r] *= alpha;
      }
    }
    #pragma unroll
    for (int r = 0; r < 4; ++r) {
      const float p0 = __builtin_amdgcn_exp2f(s[0][r] - m_[r]);
      const float p1 = __builtin_amdgcn_exp2f(s[1][r] - m_[r]);
      s[0][r] = p0; s[1][r] = p1;
      l_[r] += row16_sum(p0 + p1);
    }

    // ---- dropout (exact threefry, shiftless cmp) + f16 P to wave LDS ----
    #pragma unroll
    for (int n = 0; n < 2; ++n) {
      const int col = n * 16 + l15;
      const uint32_t jcol = (uint32_t)(kt * TK + kph * 32 + col);
      #pragma unroll
      for (int r = 0; r < 4; ++r) {
        const uint32_t bits = jax_bits(jq[r] + jcol);
        const float pf = (bits < TH9) ? s[n][r] : 0.0f;
        pwv[(quad * 4 + r) * PSTR + col] = (_Float16)pf;
      }
    }
    __threadfence_block();   // order cross-lane P writes before A-frag reads

    // ---- PV: O[16 x 128] += P[16 x 32] * V[32 x 128] (K=32, one MFMA) ----
    {
      const f16x8 ap = *(const f16x8*)&pwv[l15 * PSTR + quad * 8];
      #pragma unroll
      for (int d8 = 0; d8 < 8; ++d8) {
        const f16x8 bv = *(const f16x8*)&sVT[(d8 * 16 + l15) * VSTR + kph * 32 + quad * 8];
        accO[d8] = __builtin_amdgcn_mfma_f32_16x16x32_f16(ap, bv, accO[d8], 0, 0, 0);
      }
    }
  }

  // ---- merge the two key-phase waves of each q-group ----
  __syncthreads();   // everyone done with sK/sVT; overlay as scratch
  if (kph == 1) {
    if (l15 == 0) {
      #pragma unroll
      for (int r = 0; r < 4; ++r) {
        sM1[qg * 16 + quad * 4 + r] = m_[r];
        sL1[qg * 16 + quad * 4 + r] = l_[r];
      }
    }
    #pragma unroll
    for (int d8 = 0; d8 < 8; ++d8) {
      #pragma unroll
      for (int r = 0; r < 4; ++r)
        sO1[qg * 2048 + (quad * 4 + r) * D_ + d8 * 16 + l15] = accO[d8][r];
    }
  }
  __syncthreads();
  if (kph == 0) {
    float a0s[4], a1s[4];
    #pragma unroll
    for (int r = 0; r < 4; ++r) {
      const float m1  = sM1[qg * 16 + quad * 4 + r];
      const float l1v = sL1[qg * 16 + quad * 4 + r];
      const float mf = fmaxf(m_[r], m1);
      const float a0 = __builtin_amdgcn_exp2f(m_[r] - mf);
      const float a1 = __builtin_amdgcn_exp2f(m1 - mf);
      const float inv = 1.0f / ((a0 * l_[r] + a1 * l1v) * kp);
      a0s[r] = a0 * inv;
      a1s[r] = a1 * inv;
    }
    float* op = OUT + ((size_t)(b * S_ + qw)) * D_;
    #pragma unroll
    for (int d8 = 0; d8 < 8; ++d8) {
      #pragma unroll
      for (int r = 0; r < 4; ++r) {
        const float o1 = sO1[qg * 2048 + (quad * 4 + r) * D_ + d8 * 16 + l15];
        op[(quad * 4 + r) * D_ + d8 * 16 + l15] = accO[d8][r] * a0s[r] + o1 * a1s[r];
      }
    }
  }
}

extern "C" void kernel_launch(void* const* d_in, const int* in_sizes, int n_in,
                              void* d_out, int out_size, void* d_ws, size_t ws_size,
                              hipStream_t stream) {
  const float* q   = (const float*)d_in[0];
  const float* k   = (const float*)d_in[1];
  const float* v   = (const float*)d_in[2];
  const float* isf = (const float*)d_in[3];
  const float* dp  = (const float*)d_in[4];
  float* out = (float*)d_out;

  dim3 grid(S_ / TQ, B_);
  attn_mfma_kernel<<<grid, dim3(512), 0, stream>>>(q, k, v, isf, dp, out);
}

// Round 7
// 288.140 us; speedup vs baseline: 1.1733x; 1.1733x over previous
//
#include <hip/hip_runtime.h>
#include <stdint.h>

// B=16, S=2048, D=128 attention, per-query scale folded into Q (with log2e),
// online softmax in exp2 domain, exact JAX partitionable-threefry dropout
// (key 42, p=0.1), @V.
// Round 7: TQ=128 fat-tile — each wave owns TWO 16-row q-subtiles, so every
// staged K/V byte and every LDS fragment read feeds 2x the MFMAs, and the
// per-iteration fixed cost (2 barriers, lgkm drains, staging) is amortized
// over 2x work.  Grid 256 = 1 block/CU; register prefetch of next K/V tile.

#define B_ 16
#define S_ 2048
#define D_ 128
#define TQ 128    // q rows per block (4 groups x 32)
#define TK 64     // keys staged per iteration (each kph-wave consumes 32)
#define KSTR 136  // f16 stride for K rows (128+8): 272B, 2-way banks, 16B align
#define VSTR 72   // f16 stride for V^T rows (64+8): 144B
#define PSTR 40   // f16 stride for per-wave P rows (32+8): 80B

typedef float f32x4 __attribute__((ext_vector_type(4)));
typedef _Float16 f16x8 __attribute__((ext_vector_type(8)));
typedef _Float16 f16x2 __attribute__((ext_vector_type(2)));

union F32R { float4 q[4]; float f[16]; };

// DPP row_ror reductions over the 16 lanes of a DPP row.
#define DPP_ROR(x, ctrl) \
  __int_as_float(__builtin_amdgcn_update_dpp(0, __float_as_int(x), (ctrl), 0xf, 0xf, true))
__device__ __forceinline__ float row16_max(float x) {
  x = fmaxf(x, DPP_ROR(x, 0x128));
  x = fmaxf(x, DPP_ROR(x, 0x124));
  x = fmaxf(x, DPP_ROR(x, 0x122));
  x = fmaxf(x, DPP_ROR(x, 0x121));
  return x;
}
__device__ __forceinline__ float row16_sum(float x) {
  x += DPP_ROR(x, 0x128);
  x += DPP_ROR(x, 0x124);
  x += DPP_ROR(x, 0x122);
  x += DPP_ROR(x, 0x121);
  return x;
}

// threefry2x32, 20 rounds, key = (0, 42)  [jax.random.key(42)]
__device__ __forceinline__ uint2 threefry2x32_0_42(uint32_t x0, uint32_t x1) {
  const uint32_t k0 = 0u, k1 = 42u;
  const uint32_t k2 = 0x1BD11BDAu ^ k0 ^ k1;
  x0 += k0; x1 += k1;
#define TFR(r) { x0 += x1; x1 = __builtin_rotateleft32(x1, r); x1 ^= x0; }
  TFR(13) TFR(15) TFR(26) TFR(6)
  x0 += k1; x1 += k2 + 1u;
  TFR(17) TFR(29) TFR(16) TFR(24)
  x0 += k2; x1 += k0 + 2u;
  TFR(13) TFR(15) TFR(26) TFR(6)
  x0 += k0; x1 += k1 + 3u;
  TFR(17) TFR(29) TFR(16) TFR(24)
  x0 += k1; x1 += k2 + 4u;
  TFR(13) TFR(15) TFR(26) TFR(6)
  x0 += k2; x1 += k0 + 5u;
#undef TFR
  return make_uint2(x0, x1);
}

// HW-verified (round 2): partitionable path, counter (0, j), xor-fold.
__device__ __forceinline__ uint32_t jax_bits(uint32_t j) {
  const uint2 tf = threefry2x32_0_42(0u, j);
  return tf.x ^ tf.y;
}

__global__ __launch_bounds__(512, 2)
void attn_mfma_kernel(const float* __restrict__ Q, const float* __restrict__ K,
                      const float* __restrict__ V, const float* __restrict__ ISF,
                      const float* __restrict__ DP, float* __restrict__ OUT) {
  extern __shared__ __align__(16) char smem[];
  _Float16* const sK  = (_Float16*)smem;               // 64x136 f16  = 17408 B
  _Float16* const sVT = (_Float16*)(smem + 17408);     // 128x72 f16  = 18432 B
  _Float16* const sP  = (_Float16*)(smem + 35840);     // 8 x 32x40   = 20480 B
  // merge overlay (after final barrier):
  float* const sO1 = (float*)smem;                     // 128x128 f32 = 65536 B
  float* const sM1 = (float*)(smem + 65536);           // 128 f32
  float* const sL1 = (float*)(smem + 66048);           // 128 f32

  const int t    = threadIdx.x;
  const int lane = t & 63;
  const int l15  = lane & 15;
  const int quad = lane >> 4;
  const int w    = t >> 6;
  const int qg   = w & 3;        // q-group (32 rows)
  const int kph  = w >> 2;       // key phase: 0 = keys [0,32), 1 = [32,64)
  const int b    = blockIdx.y;
  const int qb   = blockIdx.x * TQ + qg * 32;

  const float kp = 1.0f - DP[0];
  const uint32_t TH9 = (__float_as_uint(1.0f + kp) & 0x7FFFFFu) << 9;

  float m_[2][4], l_[2][4];
  uint32_t jq[2][4];
  #pragma unroll
  for (int sub = 0; sub < 2; ++sub)
    #pragma unroll
    for (int r = 0; r < 4; ++r) {
      m_[sub][r] = -INFINITY;
      l_[sub][r] = 0.0f;
      jq[sub][r] = ((uint32_t)b << 22)
                 + (uint32_t)(qb + sub * 16 + quad * 4 + r) * (uint32_t)S_;
    }

  // ---- Q fragments (2 subtiles), f16, 1/isf and log2(e) folded in ----
  f16x8 qf[2][4];
  #pragma unroll
  for (int sub = 0; sub < 2; ++sub) {
    const int qrow = qb + sub * 16 + l15;
    const float qs = 1.4426950408889634f / ISF[b * S_ + qrow];
    const float* qp = Q + ((size_t)(b * S_ + qrow)) * D_;
    #pragma unroll
    for (int c = 0; c < 4; ++c) {
      const float4 a  = *(const float4*)(qp + c * 32 + quad * 8);
      const float4 d2 = *(const float4*)(qp + c * 32 + quad * 8 + 4);
      const float xs[8] = {a.x, a.y, a.z, a.w, d2.x, d2.y, d2.z, d2.w};
      f16x8 h;
      #pragma unroll
      for (int j = 0; j < 8; ++j) h[j] = (_Float16)(xs[j] * qs);
      qf[sub][c] = h;
    }
  }

  f32x4 accO[2][8];
  #pragma unroll
  for (int sub = 0; sub < 2; ++sub)
    #pragma unroll
    for (int i = 0; i < 8; ++i) accO[sub][i] = (f32x4){0.f, 0.f, 0.f, 0.f};

  _Float16* const pwv = &sP[w * 32 * PSTR];

  // staging decomposition (512 threads)
  const int krow = t >> 3, kcol = (t & 7) * 16;        // K: 64 rows x 128
  const int vp = t & 31, dseg = (t >> 5) * 8;          // V: 32 key-pairs x 8 d

  F32R kreg;            // prefetched K floats (16/thread)
  F32R vreg;            // prefetched V floats (8+8/thread, packed)

#define ISSUE_LOADS(KT)                                                        \
  {                                                                            \
    const float4* gk4 = (const float4*)(K +                                    \
        ((size_t)(b * S_ + (KT) * TK + krow)) * D_ + kcol);                    \
    _Pragma("unroll") for (int i = 0; i < 4; ++i) kreg.q[i] = gk4[i];          \
    const float4* gv4 = (const float4*)(V +                                    \
        ((size_t)(b * S_ + (KT) * TK + 2 * vp)) * D_ + dseg);                  \
    _Pragma("unroll") for (int i = 0; i < 2; ++i) {                            \
      vreg.q[i] = gv4[i];                                                      \
      vreg.q[i + 2] = gv4[i + 32];  /* +128 floats = next key row */           \
    }                                                                          \
  }

  ISSUE_LOADS(0)

  for (int kt = 0; kt < S_ / TK; ++kt) {
    __syncthreads();   // A: all waves done reading previous tile

    // ---- convert prefetched K -> f16 LDS ----
    {
      #pragma unroll
      for (int g = 0; g < 2; ++g) {
        f16x8 h;
        #pragma unroll
        for (int j = 0; j < 8; ++j) h[j] = (_Float16)kreg.f[g * 8 + j];
        *(f16x8*)&sK[krow * KSTR + kcol + g * 8] = h;
      }
    }
    // ---- convert prefetched V -> transposed f16 LDS ----
    {
      #pragma unroll
      for (int d = 0; d < 8; ++d) {
        f16x2 h = {(_Float16)vreg.f[d], (_Float16)vreg.f[8 + d]};
        *(f16x2*)&sVT[(dseg + d) * VSTR + 2 * vp] = h;
      }
    }
    __syncthreads();   // B: tile kt visible

    // ---- prefetch tile kt+1 into registers ----
    if (kt + 1 < S_ / TK) ISSUE_LOADS(kt + 1)

    // ---- QK^T: 2 q-subtiles x 32 keys; K-frags shared across subtiles ----
    f32x4 s[2][2];
    #pragma unroll
    for (int n = 0; n < 2; ++n) {
      f32x4 a0 = (f32x4){0.f, 0.f, 0.f, 0.f};
      f32x4 a1 = (f32x4){0.f, 0.f, 0.f, 0.f};
      #pragma unroll
      for (int c = 0; c < 4; ++c) {
        const f16x8 bh = *(const f16x8*)&sK[(kph * 32 + n * 16 + l15) * KSTR
                                            + c * 32 + quad * 8];
        a0 = __builtin_amdgcn_mfma_f32_16x16x32_f16(qf[0][c], bh, a0, 0, 0, 0);
        a1 = __builtin_amdgcn_mfma_f32_16x16x32_f16(qf[1][c], bh, a1, 0, 0, 0);
      }
      s[0][n] = a0;
      s[1][n] = a1;
    }

    // ---- online softmax (exp2 domain), per subtile ----
    float mx[2][4];
    int changed = 0;
    #pragma unroll
    for (int sub = 0; sub < 2; ++sub)
      #pragma unroll
      for (int r = 0; r < 4; ++r) {
        mx[sub][r] = row16_max(fmaxf(s[sub][0][r], s[sub][1][r]));
        changed |= (mx[sub][r] > m_[sub][r]);
      }
    if (__ballot(changed) != 0ull) {
      #pragma unroll
      for (int sub = 0; sub < 2; ++sub)
        #pragma unroll
        for (int r = 0; r < 4; ++r) {
          const float mnew = fmaxf(m_[sub][r], mx[sub][r]);
          const float alpha = __builtin_amdgcn_exp2f(m_[sub][r] - mnew);
          m_[sub][r] = mnew;
          l_[sub][r] *= alpha;
          #pragma unroll
          for (int i = 0; i < 8; ++i) accO[sub][i][r] *= alpha;
        }
    }
    #pragma unroll
    for (int sub = 0; sub < 2; ++sub)
      #pragma unroll
      for (int r = 0; r < 4; ++r) {
        const float p0 = __builtin_amdgcn_exp2f(s[sub][0][r] - m_[sub][r]);
        const float p1 = __builtin_amdgcn_exp2f(s[sub][1][r] - m_[sub][r]);
        s[sub][0][r] = p0;
        s[sub][1][r] = p1;
        l_[sub][r] += row16_sum(p0 + p1);
      }

    // ---- dropout (exact threefry) + f16 P into wave-private LDS ----
    #pragma unroll
    for (int sub = 0; sub < 2; ++sub)
      #pragma unroll
      for (int n = 0; n < 2; ++n) {
        const int col = n * 16 + l15;
        const uint32_t jcol = (uint32_t)(kt * TK + kph * 32 + col);
        #pragma unroll
        for (int r = 0; r < 4; ++r) {
          const uint32_t bits = jax_bits(jq[sub][r] + jcol);
          const float pf = (bits < TH9) ? s[sub][n][r] : 0.0f;
          pwv[(sub * 16 + quad * 4 + r) * PSTR + col] = (_Float16)pf;
        }
      }
    __threadfence_block();   // order cross-lane P writes before A-frag reads

    // ---- PV: per subtile O[16x128] += P[16x32] * V[32x128]; V shared ----
    {
      const f16x8 ap0 = *(const f16x8*)&pwv[l15 * PSTR + quad * 8];
      const f16x8 ap1 = *(const f16x8*)&pwv[(16 + l15) * PSTR + quad * 8];
      #pragma unroll
      for (int d8 = 0; d8 < 8; ++d8) {
        const f16x8 bv = *(const f16x8*)&sVT[(d8 * 16 + l15) * VSTR
                                             + kph * 32 + quad * 8];
        accO[0][d8] = __builtin_amdgcn_mfma_f32_16x16x32_f16(ap0, bv, accO[0][d8], 0, 0, 0);
        accO[1][d8] = __builtin_amdgcn_mfma_f32_16x16x32_f16(ap1, bv, accO[1][d8], 0, 0, 0);
      }
    }
  }
#undef ISSUE_LOADS

  // ---- merge the two key-phase waves of each q-group ----
  __syncthreads();   // everyone done with sK/sVT/sP; overlay as scratch
  if (kph == 1) {
    #pragma unroll
    for (int sub = 0; sub < 2; ++sub) {
      if (l15 == 0) {
        #pragma unroll
        for (int r = 0; r < 4; ++r) {
          const int gr = qg * 32 + sub * 16 + quad * 4 + r;
          sM1[gr] = m_[sub][r];
          sL1[gr] = l_[sub][r];
        }
      }
      #pragma unroll
      for (int d8 = 0; d8 < 8; ++d8)
        #pragma unroll
        for (int r = 0; r < 4; ++r) {
          const int gr = qg * 32 + sub * 16 + quad * 4 + r;
          sO1[gr * D_ + d8 * 16 + l15] = accO[sub][d8][r];
        }
    }
  }
  __syncthreads();
  if (kph == 0) {
    #pragma unroll
    for (int sub = 0; sub < 2; ++sub) {
      float a0s[4], a1s[4];
      #pragma unroll
      for (int r = 0; r < 4; ++r) {
        const int gr = qg * 32 + sub * 16 + quad * 4 + r;
        const float m1  = sM1[gr];
        const float l1v = sL1[gr];
        const float mf = fmaxf(m_[sub][r], m1);
        const float a0 = __builtin_amdgcn_exp2f(m_[sub][r] - mf);
        const float a1 = __builtin_amdgcn_exp2f(m1 - mf);
        const float inv = 1.0f / ((a0 * l_[sub][r] + a1 * l1v) * kp);
        a0s[r] = a0 * inv;
        a1s[r] = a1 * inv;
      }
      #pragma unroll
      for (int d8 = 0; d8 < 8; ++d8)
        #pragma unroll
        for (int r = 0; r < 4; ++r) {
          const int gr = qg * 32 + sub * 16 + quad * 4 + r;
          const float o1 = sO1[gr * D_ + d8 * 16 + l15];
          OUT[((size_t)(b * S_ + blockIdx.x * TQ + gr)) * D_ + d8 * 16 + l15] =
              accO[sub][d8][r] * a0s[r] + o1 * a1s[r];
        }
    }
  }
}

extern "C" void kernel_launch(void* const* d_in, const int* in_sizes, int n_in,
                              void* d_out, int out_size, void* d_ws, size_t ws_size,
                              hipStream_t stream) {
  const float* q   = (const float*)d_in[0];
  const float* k   = (const float*)d_in[1];
  const float* v   = (const float*)d_in[2];
  const float* isf = (const float*)d_in[3];
  const float* dp  = (const float*)d_in[4];
  float* out = (float*)d_out;

  dim3 grid(S_ / TQ, B_);
  attn_mfma_kernel<<<grid, dim3(512), 66560, stream>>>(q, k, v, isf, dp, out);
}

// Round 8
// 276.698 us; speedup vs baseline: 1.2218x; 1.0413x over previous
//
#include <hip/hip_runtime.h>
#include <stdint.h>

// B=16, S=2048, D=128 attention, per-query scale folded into Q (with log2e),
// online softmax in exp2 domain, exact JAX partitionable-threefry dropout
// (key 42, p=0.1), @V.
// Round 8: r7 fat tile (TQ=128, 2 q-subtiles/wave) + DOUBLE-BUFFERED K/V LDS
// -> single barrier per iteration; converts run post-PV into the next
// buffer (off the critical path); 3-stage register prefetch; threefry
// hoisted before softmax to schedule into the MFMA/DPP shadow.

#define B_ 16
#define S_ 2048
#define D_ 128
#define TQ 128    // q rows per block (4 groups x 32)
#define TK 64     // keys staged per iteration (each kph-wave consumes 32)
#define NT (S_ / TK)
#define KSTR 136  // f16 stride for K rows (128+8): 272B, 16B-aligned, 2-way banks
#define VSTR 72   // f16 stride for V^T rows (64+8): 144B
#define PSTR 40   // f16 stride for per-wave P rows (32+8): 80B

typedef float f32x4 __attribute__((ext_vector_type(4)));
typedef _Float16 f16x8 __attribute__((ext_vector_type(8)));
typedef _Float16 f16x2 __attribute__((ext_vector_type(2)));

union F32R { float4 q[4]; float f[16]; };

// DPP row_ror reductions over 16-lane row groups.
#define DPP_ROR(x, ctrl) \
  __int_as_float(__builtin_amdgcn_update_dpp(0, __float_as_int(x), (ctrl), 0xf, 0xf, true))
__device__ __forceinline__ float row16_max(float x) {
  x = fmaxf(x, DPP_ROR(x, 0x128));
  x = fmaxf(x, DPP_ROR(x, 0x124));
  x = fmaxf(x, DPP_ROR(x, 0x122));
  x = fmaxf(x, DPP_ROR(x, 0x121));
  return x;
}
__device__ __forceinline__ float row16_sum(float x) {
  x += DPP_ROR(x, 0x128);
  x += DPP_ROR(x, 0x124);
  x += DPP_ROR(x, 0x122);
  x += DPP_ROR(x, 0x121);
  return x;
}

// threefry2x32, 20 rounds, key = (0, 42)  [jax.random.key(42)]
__device__ __forceinline__ uint2 threefry2x32_0_42(uint32_t x0, uint32_t x1) {
  const uint32_t k0 = 0u, k1 = 42u;
  const uint32_t k2 = 0x1BD11BDAu ^ k0 ^ k1;
  x0 += k0; x1 += k1;
#define TFR(r) { x0 += x1; x1 = __builtin_rotateleft32(x1, r); x1 ^= x0; }
  TFR(13) TFR(15) TFR(26) TFR(6)
  x0 += k1; x1 += k2 + 1u;
  TFR(17) TFR(29) TFR(16) TFR(24)
  x0 += k2; x1 += k0 + 2u;
  TFR(13) TFR(15) TFR(26) TFR(6)
  x0 += k0; x1 += k1 + 3u;
  TFR(17) TFR(29) TFR(16) TFR(24)
  x0 += k1; x1 += k2 + 4u;
  TFR(13) TFR(15) TFR(26) TFR(6)
  x0 += k2; x1 += k0 + 5u;
#undef TFR
  return make_uint2(x0, x1);
}

// HW-verified (round 2): partitionable path, counter (0, j), xor-fold.
__device__ __forceinline__ uint32_t jax_bits(uint32_t j) {
  const uint2 tf = threefry2x32_0_42(0u, j);
  return tf.x ^ tf.y;
}

__global__ __launch_bounds__(512, 2)
void attn_mfma_kernel(const float* __restrict__ Q, const float* __restrict__ K,
                      const float* __restrict__ V, const float* __restrict__ ISF,
                      const float* __restrict__ DP, float* __restrict__ OUT) {
  extern __shared__ __align__(16) char smem[];
  _Float16* const sK0  = (_Float16*)smem;               // 64x136 f16 = 17408 B
  _Float16* const sK1  = (_Float16*)(smem + 17408);
  _Float16* const sVT0 = (_Float16*)(smem + 34816);     // 128x72 f16 = 18432 B
  _Float16* const sVT1 = (_Float16*)(smem + 53248);
  _Float16* const sP   = (_Float16*)(smem + 71680);     // 8 x 32x40 = 20480 B
  // merge overlay (after final barrier):
  float* const sO1 = (float*)smem;                      // 128x128 f32 = 65536 B
  float* const sM1 = (float*)(smem + 65536);            // 128 f32
  float* const sL1 = (float*)(smem + 66048);            // 128 f32

  const int t    = threadIdx.x;
  const int lane = t & 63;
  const int l15  = lane & 15;
  const int quad = lane >> 4;
  const int w    = t >> 6;
  const int qg   = w & 3;        // q-group (32 rows)
  const int kph  = w >> 2;       // key phase: 0 = keys [0,32), 1 = [32,64)
  const int b    = blockIdx.y;
  const int qb   = blockIdx.x * TQ + qg * 32;

  const float kp = 1.0f - DP[0];
  const uint32_t TH9 = (__float_as_uint(1.0f + kp) & 0x7FFFFFu) << 9;

  float m_[2][4], l_[2][4];
  uint32_t jq[2][4];
  #pragma unroll
  for (int sub = 0; sub < 2; ++sub)
    #pragma unroll
    for (int r = 0; r < 4; ++r) {
      m_[sub][r] = -INFINITY;
      l_[sub][r] = 0.0f;
      jq[sub][r] = ((uint32_t)b << 22)
                 + (uint32_t)(qb + sub * 16 + quad * 4 + r) * (uint32_t)S_;
    }

  // ---- Q fragments (2 subtiles), f16, 1/isf and log2(e) folded in ----
  f16x8 qf[2][4];
  #pragma unroll
  for (int sub = 0; sub < 2; ++sub) {
    const int qrow = qb + sub * 16 + l15;
    const float qs = 1.4426950408889634f / ISF[b * S_ + qrow];
    const float* qp = Q + ((size_t)(b * S_ + qrow)) * D_;
    #pragma unroll
    for (int c = 0; c < 4; ++c) {
      const float4 a  = *(const float4*)(qp + c * 32 + quad * 8);
      const float4 d2 = *(const float4*)(qp + c * 32 + quad * 8 + 4);
      const float xs[8] = {a.x, a.y, a.z, a.w, d2.x, d2.y, d2.z, d2.w};
      f16x8 h;
      #pragma unroll
      for (int j = 0; j < 8; ++j) h[j] = (_Float16)(xs[j] * qs);
      qf[sub][c] = h;
    }
  }

  f32x4 accO[2][8];
  #pragma unroll
  for (int sub = 0; sub < 2; ++sub)
    #pragma unroll
    for (int i = 0; i < 8; ++i) accO[sub][i] = (f32x4){0.f, 0.f, 0.f, 0.f};

  _Float16* const pwv = &sP[w * 32 * PSTR];

  // staging decomposition (512 threads)
  const int krow = t >> 3, kcol = (t & 7) * 16;        // K: 64 rows x 128
  const int vp = t & 31, dseg = (t >> 5) * 8;          // V: 32 key-pairs x 8 d

  F32R kreg;            // prefetched K floats (16/thread)
  F32R vreg;            // prefetched V floats (8+8/thread)

#define ISSUE_LOADS(KT)                                                        \
  {                                                                            \
    const float4* gk4 = (const float4*)(K +                                    \
        ((size_t)(b * S_ + (KT) * TK + krow)) * D_ + kcol);                    \
    _Pragma("unroll") for (int i = 0; i < 4; ++i) kreg.q[i] = gk4[i];          \
    const float4* gv4 = (const float4*)(V +                                    \
        ((size_t)(b * S_ + (KT) * TK + 2 * vp)) * D_ + dseg);                  \
    _Pragma("unroll") for (int i = 0; i < 2; ++i) {                            \
      vreg.q[i] = gv4[i];                                                      \
      vreg.q[i + 2] = gv4[i + 32];  /* +128 floats = next key row */           \
    }                                                                          \
  }

#define CONVERT_TO(KB, VB)                                                     \
  {                                                                            \
    _Pragma("unroll") for (int g = 0; g < 2; ++g) {                            \
      f16x8 h;                                                                 \
      _Pragma("unroll") for (int j = 0; j < 8; ++j)                            \
        h[j] = (_Float16)kreg.f[g * 8 + j];                                    \
      *(f16x8*)&(KB)[krow * KSTR + kcol + g * 8] = h;                          \
    }                                                                          \
    _Pragma("unroll") for (int d = 0; d < 8; ++d) {                            \
      f16x2 h = {(_Float16)vreg.f[d], (_Float16)vreg.f[8 + d]};                \
      *(f16x2*)&(VB)[(dseg + d) * VSTR + 2 * vp] = h;                          \
    }                                                                          \
  }

  // ---- pipeline prologue: tile 0 -> buf0; issue loads for tile 1 ----
  ISSUE_LOADS(0)
  CONVERT_TO(sK0, sVT0)
  ISSUE_LOADS(1)
  __syncthreads();

  for (int kt = 0; kt < NT; ++kt) {
    const int cur = kt & 1;
    _Float16* const sKc = cur ? sK1 : sK0;
    _Float16* const sVc = cur ? sVT1 : sVT0;

    // ---- QK^T: 2 q-subtiles x 32 keys; K-frags shared across subtiles ----
    f32x4 s[2][2];
    #pragma unroll
    for (int n = 0; n < 2; ++n) {
      f32x4 a0 = (f32x4){0.f, 0.f, 0.f, 0.f};
      f32x4 a1 = (f32x4){0.f, 0.f, 0.f, 0.f};
      #pragma unroll
      for (int c = 0; c < 4; ++c) {
        const f16x8 bh = *(const f16x8*)&sKc[(kph * 32 + n * 16 + l15) * KSTR
                                             + c * 32 + quad * 8];
        a0 = __builtin_amdgcn_mfma_f32_16x16x32_f16(qf[0][c], bh, a0, 0, 0, 0);
        a1 = __builtin_amdgcn_mfma_f32_16x16x32_f16(qf[1][c], bh, a1, 0, 0, 0);
      }
      s[0][n] = a0;
      s[1][n] = a1;
    }

    // ---- dropout bits (independent of scores; schedules into MFMA shadow) ----
    uint32_t rb[2][2][4];
    #pragma unroll
    for (int sub = 0; sub < 2; ++sub)
      #pragma unroll
      for (int n = 0; n < 2; ++n) {
        const uint32_t jcol = (uint32_t)(kt * TK + kph * 32 + n * 16 + l15);
        #pragma unroll
        for (int r = 0; r < 4; ++r)
          rb[sub][n][r] = jax_bits(jq[sub][r] + jcol);
      }

    // ---- online softmax (exp2 domain), per subtile ----
    float mx[2][4];
    int changed = 0;
    #pragma unroll
    for (int sub = 0; sub < 2; ++sub)
      #pragma unroll
      for (int r = 0; r < 4; ++r) {
        mx[sub][r] = row16_max(fmaxf(s[sub][0][r], s[sub][1][r]));
        changed |= (mx[sub][r] > m_[sub][r]);
      }
    if (__ballot(changed) != 0ull) {
      #pragma unroll
      for (int sub = 0; sub < 2; ++sub)
        #pragma unroll
        for (int r = 0; r < 4; ++r) {
          const float mnew = fmaxf(m_[sub][r], mx[sub][r]);
          const float alpha = __builtin_amdgcn_exp2f(m_[sub][r] - mnew);
          m_[sub][r] = mnew;
          l_[sub][r] *= alpha;
          #pragma unroll
          for (int i = 0; i < 8; ++i) accO[sub][i][r] *= alpha;
        }
    }
    #pragma unroll
    for (int sub = 0; sub < 2; ++sub)
      #pragma unroll
      for (int r = 0; r < 4; ++r) {
        const float p0 = __builtin_amdgcn_exp2f(s[sub][0][r] - m_[sub][r]);
        const float p1 = __builtin_amdgcn_exp2f(s[sub][1][r] - m_[sub][r]);
        s[sub][0][r] = p0;
        s[sub][1][r] = p1;
        l_[sub][r] += row16_sum(p0 + p1);
      }

    // ---- masked f16 P into wave-private LDS ----
    #pragma unroll
    for (int sub = 0; sub < 2; ++sub)
      #pragma unroll
      for (int n = 0; n < 2; ++n) {
        const int col = n * 16 + l15;
        #pragma unroll
        for (int r = 0; r < 4; ++r) {
          const float pf = (rb[sub][n][r] < TH9) ? s[sub][n][r] : 0.0f;
          pwv[(sub * 16 + quad * 4 + r) * PSTR + col] = (_Float16)pf;
        }
      }
    __threadfence_block();   // order cross-lane P writes before A-frag reads

    // ---- PV: per subtile O[16x128] += P[16x32] * V[32x128]; V shared ----
    {
      const f16x8 ap0 = *(const f16x8*)&pwv[l15 * PSTR + quad * 8];
      const f16x8 ap1 = *(const f16x8*)&pwv[(16 + l15) * PSTR + quad * 8];
      #pragma unroll
      for (int d8 = 0; d8 < 8; ++d8) {
        const f16x8 bv = *(const f16x8*)&sVc[(d8 * 16 + l15) * VSTR
                                             + kph * 32 + quad * 8];
        accO[0][d8] = __builtin_amdgcn_mfma_f32_16x16x32_f16(ap0, bv, accO[0][d8], 0, 0, 0);
        accO[1][d8] = __builtin_amdgcn_mfma_f32_16x16x32_f16(ap1, bv, accO[1][d8], 0, 0, 0);
      }
    }

    // ---- pipeline advance: convert kt+1 into the other buffer, then
    //      issue loads for kt+2.  Safe: buf[(kt+1)&1] readers finished at
    //      the barrier ending iter kt-1. ----
    if (kt + 1 < NT) {
      _Float16* const sKn = cur ? sK0 : sK1;
      _Float16* const sVn = cur ? sVT0 : sVT1;
      CONVERT_TO(sKn, sVn)
      if (kt + 2 < NT) ISSUE_LOADS(kt + 2)
    }
    __syncthreads();   // single barrier per iteration
  }
#undef ISSUE_LOADS
#undef CONVERT_TO

  // ---- merge the two key-phase waves of each q-group ----
  if (kph == 1) {
    #pragma unroll
    for (int sub = 0; sub < 2; ++sub) {
      if (l15 == 0) {
        #pragma unroll
        for (int r = 0; r < 4; ++r) {
          const int gr = qg * 32 + sub * 16 + quad * 4 + r;
          sM1[gr] = m_[sub][r];
          sL1[gr] = l_[sub][r];
        }
      }
      #pragma unroll
      for (int d8 = 0; d8 < 8; ++d8)
        #pragma unroll
        for (int r = 0; r < 4; ++r) {
          const int gr = qg * 32 + sub * 16 + quad * 4 + r;
          sO1[gr * D_ + d8 * 16 + l15] = accO[sub][d8][r];
        }
    }
  }
  __syncthreads();
  if (kph == 0) {
    #pragma unroll
    for (int sub = 0; sub < 2; ++sub) {
      float a0s[4], a1s[4];
      #pragma unroll
      for (int r = 0; r < 4; ++r) {
        const int gr = qg * 32 + sub * 16 + quad * 4 + r;
        const float m1  = sM1[gr];
        const float l1v = sL1[gr];
        const float mf = fmaxf(m_[sub][r], m1);
        const float a0 = __builtin_amdgcn_exp2f(m_[sub][r] - mf);
        const float a1 = __builtin_amdgcn_exp2f(m1 - mf);
        const float inv = 1.0f / ((a0 * l_[sub][r] + a1 * l1v) * kp);
        a0s[r] = a0 * inv;
        a1s[r] = a1 * inv;
      }
      #pragma unroll
      for (int d8 = 0; d8 < 8; ++d8)
        #pragma unroll
        for (int r = 0; r < 4; ++r) {
          const int gr = qg * 32 + sub * 16 + quad * 4 + r;
          const float o1 = sO1[gr * D_ + d8 * 16 + l15];
          OUT[((size_t)(b * S_ + blockIdx.x * TQ + gr)) * D_ + d8 * 16 + l15] =
              accO[sub][d8][r] * a0s[r] + o1 * a1s[r];
        }
    }
  }
}

extern "C" void kernel_launch(void* const* d_in, const int* in_sizes, int n_in,
                              void* d_out, int out_size, void* d_ws, size_t ws_size,
                              hipStream_t stream) {
  const float* q   = (const float*)d_in[0];
  const float* k   = (const float*)d_in[1];
  const float* v   = (const float*)d_in[2];
  const float* isf = (const float*)d_in[3];
  const float* dp  = (const float*)d_in[4];
  float* out = (float*)d_out;

  dim3 grid(S_ / TQ, B_);
  attn_mfma_kernel<<<grid, dim3(512), 92160, stream>>>(q, k, v, isf, dp, out);
}